// Round 10
// baseline (609.324 us; speedup 1.0000x reference)
//
#include <hip/hip_runtime.h>

#define BATCH 8192
#define V 512
#define N1 513
#define KCH 16
#define NCHUNKS 32
#define RB 16            // rows per block -> grid 512 = 2 blocks/CU
#define NT 512           // 8 waves
#define PKS 520          // Phi row stride (bf16 elems)
#define SJ 516           // S row stride (floats)

typedef __bf16 bf16_t;
typedef bf16_t bf16x8 __attribute__((ext_vector_type(8)));
typedef float f32x4 __attribute__((ext_vector_type(4)));
typedef float f32x2 __attribute__((ext_vector_type(2)));

// workspace: Mhi (EPP bf16 elems, fragment-linear triangular pack, mat=1 tiles
// PRE-NEGATED), Dv (fp32, pre-scaled by mat sign), Bv (fp32, pre-negated mat=1).
//   chunk cc in 1..31: nkb = ceil(cc/2) k-blocks of 32 (zero-pad past 16*cc);
//   base elems = 16384*floor(cc^2/4); elem = base + (kb*32 + t)*512 + lane*8 + jj
//   with t = 2*vl + mat, lane = c + 16*q, k = kb*32 + 8*q + jj.
// Dv: [cc][vl][512 j], j = 32*vlo + 16*mat + c. Bv: [cc][512 j].
#define EPP 4194304ull
#define DV_OFF (EPP * 2ull)
#define BV_OFF (DV_OFF + 1048576ull)

__device__ __forceinline__ f32x4 mfma16(bf16x8 a, bf16x8 b, f32x4 c) {
    return __builtin_amdgcn_mfma_f32_16x16x32_bf16(a, b, c, 0, 0, 0);
}

// ---- unified repack: blocks 0..495 pack Mhi; 496..1583 pack Dv/Bv -------------
__global__ __launch_bounds__(256)
void repack_all(const float* __restrict__ pos, const float* __restrict__ neg,
                bf16_t* __restrict__ Mhi, float* __restrict__ Dv,
                float* __restrict__ Bv)
{
    const int bx = blockIdx.x;
    if (bx < 496) {
        const int cc  = (bx >> 4) + 1;       // 1..31
        const int kb  = bx & 15;
        const int nkb = (cc + 1) >> 1;
        if (kb >= nkb) return;
        const int klen = 16 * cc;
        const size_t base = 16384ull * (size_t)((cc * cc) / 4) + (size_t)kb * 16384ull;
        for (int e = threadIdx.x; e < 16384; e += 256) {
            const int t = e >> 9, s = (e >> 3) & 63, jj = e & 7;
            const int c = s & 15, q = s >> 4;
            const int v = cc * 16 + (t >> 1);
            const int k = kb * 32 + 8 * q + jj;
            const float* src = (t & 1) ? neg : pos;
            float x = (k < klen) ? src[(size_t)(v * 16 + c) * N1 + k] : 0.0f;
            if (t & 1) x = -x;               // pre-negate mat=1
            Mhi[base + e] = (bf16_t)x;
        }
    } else {
        const int e = (bx - 496) * 256 + threadIdx.x;
        if (e < 262144) {
            const int cc = e >> 13, vl = (e >> 9) & 15, j = e & 511;
            const int v = cc * 16 + (j >> 5), c = j & 15;
            const float* src = (j & 16) ? neg : pos;
            const float x = src[(size_t)(v * 16 + c) * N1 + cc * 16 + vl];
            Dv[e] = (j & 16) ? -x : x;       // pre-scale by mat sign
        } else {
            const int e2 = e - 262144;
            const int cc = e2 >> 9, j = e2 & 511;
            const int v = cc * 16 + (j >> 5), c = j & 15;
            const float* src = (j & 16) ? neg : pos;
            const float x = src[(size_t)(v * 16 + c) * N1 + V];
            Bv[e2] = (j & 16) ? -x : x;      // pre-negate mat=1 bias
        }
    }
}

// ---- fused main kernel (16-row blocks, grid 512 -> 2 blocks/CU) ----------------
// Per chunk cc: dump acc -> S (one pass, 16 rows), barrier, in-wave barrier-free
// 16-step chain (wave w owns rows 2w..2w+1) interleaving chunk cc+1's bulk GEMM
// k-blocks; barrier; one final zero-padded k-block completes acc(cc+1).
// mat=1 values live negated end-to-end: every reduce is max, upper = -red.
// NOTE: min-waves bound stays 2 — bound 4 forced a 64/64 arch/acc split and
// catastrophic spill at RB=32 (R8). 4 waves/SIMD comes from actual VGPR<=128.
__global__ __launch_bounds__(NT, 2)
void shield_fused(const float* __restrict__ preds,
                  const bf16_t* __restrict__ Mhi,
                  const float* __restrict__ Dv, const float* __restrict__ Bv,
                  float* __restrict__ out)
{
    __shared__ bf16_t Phi[RB * PKS];   // 16,640 B
    __shared__ float  S[RB * SJ];      // 33,024 B  (total 49,664 -> 2 blocks/CU)

    const int tid  = threadIdx.x;
    const int b0   = blockIdx.x * RB;
    const int lane = tid & 63;
    const int w    = tid >> 6;
    const int cq   = lane & 15;
    const int q    = lane >> 4;
    const int rp0  = w * 2;            // chain rows 2w, 2w+1

    // ---- load preds -> Phi ----
    {
        const int r = tid >> 5, seg = tid & 31;
        const float* prow = preds + (size_t)(b0 + r) * V + seg * 16;
        #pragma unroll
        for (int k = 0; k < 16; k += 4) {
            const float4 p4 = *(const float4*)(prow + k);
            const int n = seg * 16 + k;
            Phi[r * PKS + n + 0] = (bf16_t)p4.x;
            Phi[r * PKS + n + 1] = (bf16_t)p4.y;
            Phi[r * PKS + n + 2] = (bf16_t)p4.z;
            Phi[r * PKS + n + 3] = (bf16_t)p4.w;
        }
    }

    int tJ[4];
    #pragma unroll
    for (int tt = 0; tt < 4; ++tt) tJ[tt] = ((4 * w + tt) << 4) + cq;
    const int aoff = cq * PKS + 8 * q;

    // acc(0) = bias(0)
    f32x4 acc[4];
    #pragma unroll
    for (int tt = 0; tt < 4; ++tt) {
        const float b = Bv[tJ[tt]];
        acc[tt] = f32x4{b, b, b, b};
    }

    #pragma unroll 1
    for (int cc = 0; cc < NCHUNKS; ++cc) {
        const int v0 = cc * 16;
        const int  ccn  = cc + 1;
        const bool hasN = ccn < NCHUNKS;
        const int  nkbN = hasN ? ((ccn + 1) >> 1) : 0;
        const bf16_t* phN = Mhi + 16384ull * (size_t)((ccn * ccn) / 4)
                          + (size_t)lane * 8 + (size_t)(4 * w) * 512;

        // ---- dump acc(cc) -> S (C-frag rows 4q+reg cover all 16) ----
        #pragma unroll
        for (int tt = 0; tt < 4; ++tt)
            #pragma unroll
            for (int reg = 0; reg < 4; ++reg)
                S[(4 * q + reg) * SJ + tJ[tt]] = acc[tt][reg];
        __syncthreads();   // (A) S ready; prev chain's Phi writes visible

        // ---- load s2: lane owns j = 8*lane..8*lane+7, rows 2w / 2w+1 ----
        f32x2 s2[8];
        {
            const float4 a0 = *(const float4*)(&S[rp0 * SJ + 8 * lane]);
            const float4 a1 = *(const float4*)(&S[rp0 * SJ + 8 * lane + 4]);
            const float4 c0 = *(const float4*)(&S[(rp0 + 1) * SJ + 8 * lane]);
            const float4 c1 = *(const float4*)(&S[(rp0 + 1) * SJ + 8 * lane + 4]);
            s2[0] = f32x2{a0.x, c0.x}; s2[1] = f32x2{a0.y, c0.y};
            s2[2] = f32x2{a0.z, c0.z}; s2[3] = f32x2{a0.w, c0.w};
            s2[4] = f32x2{a1.x, c1.x}; s2[5] = f32x2{a1.y, c1.y};
            s2[6] = f32x2{a1.z, c1.z}; s2[7] = f32x2{a1.w, c1.w};
        }

        // ---- init acc(ccn) with bias ----
        if (hasN) {
            #pragma unroll
            for (int tt = 0; tt < 4; ++tt) {
                const float b = Bv[(ccn << 9) + tJ[tt]];
                acc[tt] = f32x4{b, b, b, b};
            }
        }

        // ---- 16-step serial chain + interleaved bulk GEMM of chunk ccn ----
        #pragma unroll
        for (int vl = 0; vl < KCH; ++vl) {
            const int vcur = v0 + vl;
            const bool doKb = hasN && (vl < nkbN - 1);

            bf16x8 fa, fb0, fb1, fb2, fb3;
            if (doKb) {
                const int k0 = vl * 32;
                fa = *(const bf16x8*)(Phi + aoff + k0);
                const bf16_t* pb = phN + (size_t)k0 * 512;
                fb0 = *(const bf16x8*)(pb);
                fb1 = *(const bf16x8*)(pb + 512);
                fb2 = *(const bf16x8*)(pb + 1024);
                fb3 = *(const bf16x8*)(pb + 1536);
            }

            // this step's dv (global, L2-hot) and po (LDS); consumed post-reduce
            float dv[8], po[2];
            {
                const float* dp = Dv + ((size_t)vcur << 9) + 8 * lane;
                const float4 d0 = *(const float4*)(dp);
                const float4 d1 = *(const float4*)(dp + 4);
                dv[0]=d0.x; dv[1]=d0.y; dv[2]=d0.z; dv[3]=d0.w;
                dv[4]=d1.x; dv[5]=d1.y; dv[6]=d1.z; dv[7]=d1.w;
                po[0] = (float)Phi[rp0 * PKS + vcur];
                po[1] = (float)Phi[(rp0 + 1) * PKS + vcur];
            }

            // reduce 8 -> 1 per row, merge ch partner (xor 1)
            float red[2];
            #pragma unroll
            for (int r = 0; r < 2; ++r) {
                const float x = fmaxf(fmaxf(s2[0][r], s2[1][r]),
                                      fmaxf(s2[2][r], s2[3][r]));
                const float y = fmaxf(fmaxf(s2[4][r], s2[5][r]),
                                      fmaxf(s2[6][r], s2[7][r]));
                const float m = fmaxf(x, y);
                red[r] = fmaxf(m, __shfl_xor(m, 1, 64));
            }
            float pc[2];
            #pragma unroll
            for (int r = 0; r < 2; ++r) {
                const float lw  = __shfl(red[r], 4 * vl, 64);       // lower
                const float nup = __shfl(red[r], 4 * vl + 2, 64);   // -upper
                pc[r] = fminf(fmaxf(po[r], lw), -nup);
            }
            if (lane == 4 * vl) {
                Phi[rp0 * PKS + vcur]       = (bf16_t)pc[0];
                Phi[(rp0 + 1) * PKS + vcur] = (bf16_t)pc[1];
            }
            // rank-1 update (packed fp32 fma; Dv pre-scaled so no sign mul)
            const f32x2 pcv = {pc[0], pc[1]};
            #pragma unroll
            for (int jj = 0; jj < 8; ++jj) {
                const f32x2 dsp = {dv[jj], dv[jj]};
                s2[jj] = __builtin_elementwise_fma(dsp, pcv, s2[jj]);
            }

            if (doKb) {
                acc[0] = mfma16(fa, fb0, acc[0]);
                acc[1] = mfma16(fa, fb1, acc[1]);
                acc[2] = mfma16(fa, fb2, acc[2]);
                acc[3] = mfma16(fa, fb3, acc[3]);
            }
        }

        __syncthreads();   // (D) fresh Phi columns visible to all waves

        // ---- final k-block of chunk ccn (zero-padded B -> exact no-ops) ----
        if (hasN) {
            const int k0 = (nkbN - 1) * 32;
            const bf16x8 fa = *(const bf16x8*)(Phi + aoff + k0);
            const bf16_t* pb = phN + (size_t)k0 * 512;
            const bf16x8 fb0 = *(const bf16x8*)(pb);
            const bf16x8 fb1 = *(const bf16x8*)(pb + 512);
            const bf16x8 fb2 = *(const bf16x8*)(pb + 1024);
            const bf16x8 fb3 = *(const bf16x8*)(pb + 1536);
            acc[0] = mfma16(fa, fb0, acc[0]);
            acc[1] = mfma16(fa, fb1, acc[1]);
            acc[2] = mfma16(fa, fb2, acc[2]);
            acc[3] = mfma16(fa, fb3, acc[3]);
        }
    }

    // ---- epilogue ----
    {
        const int r = tid >> 5, seg = tid & 31;
        float* orow = out + (size_t)(b0 + r) * V + seg * 16;
        #pragma unroll
        for (int k = 0; k < 16; k += 4) {
            const int n = seg * 16 + k;
            float4 o;
            o.x = (float)Phi[r * PKS + n + 0];
            o.y = (float)Phi[r * PKS + n + 1];
            o.z = (float)Phi[r * PKS + n + 2];
            o.w = (float)Phi[r * PKS + n + 3];
            *(float4*)(orow + k) = o;
        }
    }
}

extern "C" void kernel_launch(void* const* d_in, const int* in_sizes, int n_in,
                              void* d_out, int out_size, void* d_ws, size_t ws_size,
                              hipStream_t stream) {
    const float* preds = (const float*)d_in[0];
    const float* pos   = (const float*)d_in[1];
    const float* neg   = (const float*)d_in[2];
    float* o = (float*)d_out;
    char* base = (char*)d_ws;
    bf16_t* Mhi = (bf16_t*)base;
    float*  Dv  = (float*)(base + DV_OFF);
    float*  Bv  = (float*)(base + BV_OFF);
    repack_all<<<dim3(1584), 256, 0, stream>>>(pos, neg, Mhi, Dv, Bv);
    shield_fused<<<dim3(BATCH / RB), NT, 0, stream>>>(preds, Mhi, Dv, Bv, o);
}

// Round 11
// 420.221 us; speedup vs baseline: 1.4500x; 1.4500x over previous
//
#include <hip/hip_runtime.h>

#define BATCH 8192
#define V 512
#define N1 513
#define KCH 16
#define NCHUNKS 32
#define RB 32            // rows per block -> grid 256
#define NT 1024          // 16 waves in ONE block -> 4 waves/SIMD guaranteed
#define PKS 520          // Phi row stride (bf16 elems)
#define SJ 516           // S row stride (floats)

typedef __bf16 bf16_t;
typedef bf16_t bf16x8 __attribute__((ext_vector_type(8)));
typedef float f32x4 __attribute__((ext_vector_type(4)));
typedef float f32x2 __attribute__((ext_vector_type(2)));

// workspace: Mhi (fragment-linear triangular pack, mat=1 tiles PRE-NEGATED),
// Dv (fp32, pre-scaled by mat sign), Bv (fp32, pre-negated mat=1).
//   chunk cc in 1..31: nkb = ceil(cc/2) k-blocks of 32 (zero-pad past 16*cc);
//   base elems = 16384*floor(cc^2/4); elem = base + (kb*32 + t)*512 + lane*8 + jj
//   with t = 2*vl + mat, lane = c + 16*q, k = kb*32 + 8*q + jj.
// Dv: [cc][vl][512 j], j = 32*vlo + 16*mat + c. Bv: [cc][512 j].
#define EPP 4194304ull
#define DV_OFF (EPP * 2ull)
#define BV_OFF (DV_OFF + 1048576ull)

__device__ __forceinline__ f32x4 mfma16(bf16x8 a, bf16x8 b, f32x4 c) {
    return __builtin_amdgcn_mfma_f32_16x16x32_bf16(a, b, c, 0, 0, 0);
}

// ---- unified repack: blocks 0..495 pack Mhi; 496..1583 pack Dv/Bv -------------
__global__ __launch_bounds__(256)
void repack_all(const float* __restrict__ pos, const float* __restrict__ neg,
                bf16_t* __restrict__ Mhi, float* __restrict__ Dv,
                float* __restrict__ Bv)
{
    const int bx = blockIdx.x;
    if (bx < 496) {
        const int cc  = (bx >> 4) + 1;       // 1..31
        const int kb  = bx & 15;
        const int nkb = (cc + 1) >> 1;
        if (kb >= nkb) return;
        const int klen = 16 * cc;
        const size_t base = 16384ull * (size_t)((cc * cc) / 4) + (size_t)kb * 16384ull;
        for (int e = threadIdx.x; e < 16384; e += 256) {
            const int t = e >> 9, s = (e >> 3) & 63, jj = e & 7;
            const int c = s & 15, q = s >> 4;
            const int v = cc * 16 + (t >> 1);
            const int k = kb * 32 + 8 * q + jj;
            const float* src = (t & 1) ? neg : pos;
            float x = (k < klen) ? src[(size_t)(v * 16 + c) * N1 + k] : 0.0f;
            if (t & 1) x = -x;               // pre-negate mat=1
            Mhi[base + e] = (bf16_t)x;
        }
    } else {
        const int e = (bx - 496) * 256 + threadIdx.x;
        if (e < 262144) {
            const int cc = e >> 13, vl = (e >> 9) & 15, j = e & 511;
            const int v = cc * 16 + (j >> 5), c = j & 15;
            const float* src = (j & 16) ? neg : pos;
            const float x = src[(size_t)(v * 16 + c) * N1 + cc * 16 + vl];
            Dv[e] = (j & 16) ? -x : x;       // pre-scale by mat sign
        } else {
            const int e2 = e - 262144;
            const int cc = e2 >> 9, j = e2 & 511;
            const int v = cc * 16 + (j >> 5), c = j & 15;
            const float* src = (j & 16) ? neg : pos;
            const float x = src[(size_t)(v * 16 + c) * N1 + V];
            Bv[e2] = (j & 16) ? -x : x;      // pre-negate mat=1 bias
        }
    }
}

// ---- fused main kernel: 32 rows, 16 waves, grid 256 ----------------------------
// Wave w: GEMM j-tiles t = 2w..2w+1 (both 16-row halves, acc[2][2]); chain owns
// rows 2w..2w+1. Per chunk: dump acc -> S, barrier, 16-step barrier-free in-wave
// chain interleaving chunk cc+1's bulk GEMM k-blocks, barrier, final k-block.
// mat=1 values live negated end-to-end: every reduce is max, upper = -red.
// NOTE: launch_bounds(1024) forces VGPR<=128 (16 waves must co-reside); live
// state ~90 regs so no spill (R8's spill came from needing >128).
__global__ __launch_bounds__(NT)
void shield_fused(const float* __restrict__ preds,
                  const bf16_t* __restrict__ Mhi,
                  const float* __restrict__ Dv, const float* __restrict__ Bv,
                  float* __restrict__ out)
{
    __shared__ bf16_t Phi[RB * PKS];   // 33,280 B
    __shared__ float  S[RB * SJ];      // 66,048 B  (total 99,328 -> 1 block/CU)

    const int tid  = threadIdx.x;
    const int b0   = blockIdx.x * RB;
    const int lane = tid & 63;
    const int w    = tid >> 6;          // 0..15
    const int cq   = lane & 15;
    const int q    = lane >> 4;
    const int rp0  = w * 2;             // chain rows 2w, 2w+1

    // ---- load preds -> Phi ----
    {
        const int r = tid >> 5, seg = tid & 31;
        const float* prow = preds + (size_t)(b0 + r) * V + seg * 16;
        #pragma unroll
        for (int k = 0; k < 16; k += 4) {
            const float4 p4 = *(const float4*)(prow + k);
            const int n = seg * 16 + k;
            Phi[r * PKS + n + 0] = (bf16_t)p4.x;
            Phi[r * PKS + n + 1] = (bf16_t)p4.y;
            Phi[r * PKS + n + 2] = (bf16_t)p4.z;
            Phi[r * PKS + n + 3] = (bf16_t)p4.w;
        }
    }

    int tJ[2];
    #pragma unroll
    for (int tt = 0; tt < 2; ++tt) tJ[tt] = ((2 * w + tt) << 4) + cq;
    const int aoff0 = cq * PKS + 8 * q;
    const int aoff1 = (16 + cq) * PKS + 8 * q;

    // acc(0) = bias(0)
    f32x4 acc[2][2];
    #pragma unroll
    for (int tt = 0; tt < 2; ++tt) {
        const float b = Bv[tJ[tt]];
        acc[0][tt] = f32x4{b, b, b, b};
        acc[1][tt] = f32x4{b, b, b, b};
    }

    #pragma unroll 1
    for (int cc = 0; cc < NCHUNKS; ++cc) {
        const int v0 = cc * 16;
        const int  ccn  = cc + 1;
        const bool hasN = ccn < NCHUNKS;
        const int  nkbN = hasN ? ((ccn + 1) >> 1) : 0;
        const bf16_t* phN = Mhi + 16384ull * (size_t)((ccn * ccn) / 4)
                          + (size_t)lane * 8 + (size_t)(2 * w) * 512;

        // ---- dump acc(cc) -> S ----
        #pragma unroll
        for (int tt = 0; tt < 2; ++tt)
            #pragma unroll
            for (int reg = 0; reg < 4; ++reg) {
                S[(4 * q + reg) * SJ + tJ[tt]]      = acc[0][tt][reg];
                S[(16 + 4 * q + reg) * SJ + tJ[tt]] = acc[1][tt][reg];
            }
        __syncthreads();   // (A) S ready; prior Phi writes visible

        // ---- load s2: lane owns j = 8*lane..8*lane+7, rows 2w / 2w+1 ----
        f32x2 s2[8];
        {
            const float4 a0 = *(const float4*)(&S[rp0 * SJ + 8 * lane]);
            const float4 a1 = *(const float4*)(&S[rp0 * SJ + 8 * lane + 4]);
            const float4 c0 = *(const float4*)(&S[(rp0 + 1) * SJ + 8 * lane]);
            const float4 c1 = *(const float4*)(&S[(rp0 + 1) * SJ + 8 * lane + 4]);
            s2[0] = f32x2{a0.x, c0.x}; s2[1] = f32x2{a0.y, c0.y};
            s2[2] = f32x2{a0.z, c0.z}; s2[3] = f32x2{a0.w, c0.w};
            s2[4] = f32x2{a1.x, c1.x}; s2[5] = f32x2{a1.y, c1.y};
            s2[6] = f32x2{a1.z, c1.z}; s2[7] = f32x2{a1.w, c1.w};
        }

        // ---- init acc(ccn) with bias ----
        if (hasN) {
            #pragma unroll
            for (int tt = 0; tt < 2; ++tt) {
                const float b = Bv[(ccn << 9) + tJ[tt]];
                acc[0][tt] = f32x4{b, b, b, b};
                acc[1][tt] = f32x4{b, b, b, b};
            }
        }

        // ---- 16-step serial chain + interleaved bulk GEMM of chunk ccn ----
        #pragma unroll
        for (int vl = 0; vl < KCH; ++vl) {
            const int vcur = v0 + vl;
            const bool doKb = hasN && (vl < nkbN - 1);

            bf16x8 fa0, fa1, fb0, fb1;
            if (doKb) {
                const int k0 = vl * 32;
                fa0 = *(const bf16x8*)(Phi + aoff0 + k0);
                fa1 = *(const bf16x8*)(Phi + aoff1 + k0);
                const bf16_t* pb = phN + (size_t)k0 * 512;
                fb0 = *(const bf16x8*)(pb);
                fb1 = *(const bf16x8*)(pb + 512);
            }

            // this step's dv (global, L2-hot) and po (LDS); consumed post-reduce
            float dv[8], po[2];
            {
                const float* dp = Dv + ((size_t)vcur << 9) + 8 * lane;
                const float4 d0 = *(const float4*)(dp);
                const float4 d1 = *(const float4*)(dp + 4);
                dv[0]=d0.x; dv[1]=d0.y; dv[2]=d0.z; dv[3]=d0.w;
                dv[4]=d1.x; dv[5]=d1.y; dv[6]=d1.z; dv[7]=d1.w;
                po[0] = (float)Phi[rp0 * PKS + vcur];
                po[1] = (float)Phi[(rp0 + 1) * PKS + vcur];
            }

            // packed in-lane reduce 8 -> 1 (both rows at once), merge ch (xor 1)
            f32x2 m01 = __builtin_elementwise_max(s2[0], s2[1]);
            f32x2 m23 = __builtin_elementwise_max(s2[2], s2[3]);
            f32x2 m45 = __builtin_elementwise_max(s2[4], s2[5]);
            f32x2 m67 = __builtin_elementwise_max(s2[6], s2[7]);
            f32x2 mx  = __builtin_elementwise_max(
                            __builtin_elementwise_max(m01, m23),
                            __builtin_elementwise_max(m45, m67));
            float red[2];
            #pragma unroll
            for (int r = 0; r < 2; ++r)
                red[r] = fmaxf(mx[r], __shfl_xor(mx[r], 1, 64));
            float pc[2];
            #pragma unroll
            for (int r = 0; r < 2; ++r) {
                const float lw  = __shfl(red[r], 4 * vl, 64);       // lower
                const float nup = __shfl(red[r], 4 * vl + 2, 64);   // -upper
                pc[r] = fminf(fmaxf(po[r], lw), -nup);
            }
            if (lane == 4 * vl) {
                Phi[rp0 * PKS + vcur]       = (bf16_t)pc[0];
                Phi[(rp0 + 1) * PKS + vcur] = (bf16_t)pc[1];
            }
            // rank-1 update (packed fp32 fma; Dv pre-scaled so no sign mul)
            const f32x2 pcv = {pc[0], pc[1]};
            #pragma unroll
            for (int jj = 0; jj < 8; ++jj) {
                const f32x2 dsp = {dv[jj], dv[jj]};
                s2[jj] = __builtin_elementwise_fma(dsp, pcv, s2[jj]);
            }

            if (doKb) {
                acc[0][0] = mfma16(fa0, fb0, acc[0][0]);
                acc[1][0] = mfma16(fa1, fb0, acc[1][0]);
                acc[0][1] = mfma16(fa0, fb1, acc[0][1]);
                acc[1][1] = mfma16(fa1, fb1, acc[1][1]);
            }
        }

        __syncthreads();   // (D) fresh Phi columns visible; S safe to reuse

        // ---- final k-block of chunk ccn (zero-padded B -> exact no-ops) ----
        if (hasN) {
            const int k0 = (nkbN - 1) * 32;
            const bf16x8 fa0 = *(const bf16x8*)(Phi + aoff0 + k0);
            const bf16x8 fa1 = *(const bf16x8*)(Phi + aoff1 + k0);
            const bf16_t* pb = phN + (size_t)k0 * 512;
            const bf16x8 fb0 = *(const bf16x8*)(pb);
            const bf16x8 fb1 = *(const bf16x8*)(pb + 512);
            acc[0][0] = mfma16(fa0, fb0, acc[0][0]);
            acc[1][0] = mfma16(fa1, fb0, acc[1][0]);
            acc[0][1] = mfma16(fa0, fb1, acc[0][1]);
            acc[1][1] = mfma16(fa1, fb1, acc[1][1]);
        }
    }

    // ---- epilogue ----
    {
        const int r = tid >> 5, seg = tid & 31;
        float* orow = out + (size_t)(b0 + r) * V + seg * 16;
        #pragma unroll
        for (int k = 0; k < 16; k += 4) {
            const int n = seg * 16 + k;
            float4 o;
            o.x = (float)Phi[r * PKS + n + 0];
            o.y = (float)Phi[r * PKS + n + 1];
            o.z = (float)Phi[r * PKS + n + 2];
            o.w = (float)Phi[r * PKS + n + 3];
            *(float4*)(orow + k) = o;
        }
    }
}

extern "C" void kernel_launch(void* const* d_in, const int* in_sizes, int n_in,
                              void* d_out, int out_size, void* d_ws, size_t ws_size,
                              hipStream_t stream) {
    const float* preds = (const float*)d_in[0];
    const float* pos   = (const float*)d_in[1];
    const float* neg   = (const float*)d_in[2];
    float* o = (float*)d_out;
    char* base = (char*)d_ws;
    bf16_t* Mhi = (bf16_t*)base;
    float*  Dv  = (float*)(base + DV_OFF);
    float*  Bv  = (float*)(base + BV_OFF);
    repack_all<<<dim3(1584), 256, 0, stream>>>(pos, neg, Mhi, Dv, Bv);
    shield_fused<<<dim3(BATCH / RB), NT, 0, stream>>>(preds, Mhi, Dv, Bv, o);
}